// Round 3
// baseline (443.352 us; speedup 1.0000x reference)
//
#include <hip/hip_runtime.h>
#include <hip/hip_bf16.h>

// GCN 2-layer. CSR via block-local radix partition, 16-padded lists (dummy node N).
// h' = isd*(x@W1) and h2' = isd*(h1@W2) pre-scaled at the producer => agg loops are
// pure {index load, row gather, unpack, add}. Intermediates bf16. GEMM1 = bf16 MFMA.
// R2/R3: gather tables column-split into 2 planes pinned to XCD halves (blockIdx%8).
//     Per-XCD L2 working set halves (h': 12.8MB/plane; h2': 4MB/plane = L2-resident)
//     => L2-miss (FETCH) traffic toward the 8*plane compulsory floor.
//     (R2 bench was an infra failure; R3 = identical resubmit.)

#define CHUNK   4096              // edges per partition block (392 blocks)
#define NPB     512               // nodes per bucket (dst >> 9)
#define NBUCK   196               // ceil(100000/512)
#define BBCAP   9216              // bucket capacity (mean 8163, +11 sigma)

typedef __bf16 bf16x8 __attribute__((ext_vector_type(8)));
typedef float floatx4 __attribute__((ext_vector_type(4)));

__device__ inline unsigned short f2bf(float f) {      // RNE fp32->bf16
    unsigned u = __float_as_uint(f);
    u += 0x7FFF + ((u >> 16) & 1);
    return (unsigned short)(u >> 16);
}
__device__ inline float bflo(unsigned p) { return __uint_as_float(p << 16); }
__device__ inline float bfhi(unsigned p) { return __uint_as_float(p & 0xFFFF0000u); }

// ---------------- pass 1: block-local radix partition by dst>>9 ----------------
// rec = src (17b) | (dst&511)<<17
__global__ __launch_bounds__(256) void k_part(const int* __restrict__ src,
                                              const int* __restrict__ dst,
                                              int* __restrict__ gcursor,
                                              unsigned* __restrict__ buckets, int E) {
    __shared__ unsigned srec[CHUNK];          // 16 KB
    __shared__ unsigned char sb8[CHUNK];      // 4 KB
    __shared__ int hist[NBUCK];
    __shared__ int lbase[NBUCK];
    __shared__ int gbase[NBUCK];
    __shared__ int scanbuf[256];
    int t = threadIdx.x;
    int base = blockIdx.x * CHUNK;
    int cnt = min(CHUNK, E - base);           // multiple of 4
    for (int i = t; i < NBUCK; i += 256) hist[i] = 0;
    __syncthreads();

    unsigned rec[16];
    unsigned br[16];                          // b (8b) | rank<<8
    bool valid[4];
    #pragma unroll
    for (int k = 0; k < 4; ++k) {
        int e0 = k * 1024 + t * 4;
        valid[k] = (e0 < cnt);
        if (valid[k]) {
            int4 s4 = *(const int4*)&src[base + e0];
            int4 d4 = *(const int4*)&dst[base + e0];
            int ss[4] = {s4.x, s4.y, s4.z, s4.w};
            int dd[4] = {d4.x, d4.y, d4.z, d4.w};
            #pragma unroll
            for (int j = 0; j < 4; ++j) {
                int b = dd[j] >> 9;
                int r = atomicAdd(&hist[b], 1);           // LDS atomic
                rec[k * 4 + j] = (unsigned)ss[j] | ((unsigned)(dd[j] & 511) << 17);
                br[k * 4 + j] = (unsigned)b | ((unsigned)r << 8);
            }
        }
    }
    __syncthreads();
    // inclusive Hillis-Steele scan over 256 (NBUCK padded)
    scanbuf[t] = (t < NBUCK) ? hist[t] : 0;
    __syncthreads();
    for (int s = 1; s < 256; s <<= 1) {
        int v = (t >= s) ? scanbuf[t - s] : 0;
        __syncthreads();
        scanbuf[t] += v;
        __syncthreads();
    }
    if (t < NBUCK) {
        lbase[t] = scanbuf[t] - hist[t];                  // exclusive base
        gbase[t] = atomicAdd(&gcursor[t], hist[t]);       // per-bucket global atomic
    }
    __syncthreads();
    // reorder into LDS, grouped by bucket
    #pragma unroll
    for (int k = 0; k < 4; ++k) {
        if (valid[k]) {
            #pragma unroll
            for (int j = 0; j < 4; ++j) {
                unsigned b = br[k * 4 + j] & 255u;
                unsigned r = br[k * 4 + j] >> 8;
                int p = lbase[b] + (int)r;
                srec[p] = rec[k * 4 + j];
                sb8[p] = (unsigned char)b;
            }
        }
    }
    __syncthreads();
    // dense flat write
    for (int i = t; i < cnt; i += 256) {
        int b = sb8[i];
        int pos = gbase[b] + (i - lbase[b]);
        if (pos < BBCAP) buckets[(size_t)b * BBCAP + pos] = srec[i];
    }
}

// ---------------- pass 2a: per-bucket deg histogram (dense) ----------------
__global__ __launch_bounds__(256) void k_count(const unsigned* __restrict__ buckets,
                                               const int* __restrict__ gcursor,
                                               int* __restrict__ deg, int N) {
    __shared__ int hist[NPB];
    int b = blockIdx.x;
    for (int i = threadIdx.x; i < NPB; i += 256) hist[i] = 0;
    __syncthreads();
    int cnt = min(gcursor[b], BBCAP);
    const unsigned* bk = &buckets[(size_t)b * BBCAP];
    for (int i = threadIdx.x; i < cnt; i += 256)
        atomicAdd(&hist[bk[i] >> 17], 1);
    __syncthreads();
    int node0 = b << 9;
    for (int i = threadIdx.x; i < NPB; i += 256)
        if (node0 + i < N) deg[node0 + i] = hist[i];
}

// ---------------- isd + offsets over PADDED degree ----------------
__global__ void k_isd_offsets(const int* __restrict__ deg, float* __restrict__ isd,
                              int* __restrict__ offsets, int* __restrict__ counter, int N) {
    int n = blockIdx.x * blockDim.x + threadIdx.x;
    int lane = threadIdx.x & 63;
    int d = (n < N) ? deg[n] : 0;
    if (n <= N) isd[n] = (d > 0) ? rsqrtf((float)d) : 0.f;   // isd[N]=0 dummy
    int dp = (d + 15) & ~15;                  // padded degree
    int pref = dp;
    #pragma unroll
    for (int sh = 1; sh < 64; sh <<= 1) {
        int t = __shfl_up(pref, sh);
        if (lane >= sh) pref += t;
    }
    int total = __shfl(pref, 63);
    int base = 0;
    if (lane == 63) base = atomicAdd(counter, total);
    base = __shfl(base, 63);
    if (n < N) offsets[n] = base + pref - dp;
}

// ---------------- pass 2b: placement via LDS cursors + dummy-pad fill ----------------
__global__ __launch_bounds__(256) void k_place(const unsigned* __restrict__ buckets,
                                               const int* __restrict__ gcursor,
                                               const int* __restrict__ offsets,
                                               const int* __restrict__ deg,
                                               int* __restrict__ csr, int N) {
    __shared__ int cur[NPB];
    int b = blockIdx.x;
    int node0 = b << 9;
    for (int i = threadIdx.x; i < NPB; i += 256)
        cur[i] = (node0 + i < N) ? offsets[node0 + i] : 0;
    __syncthreads();
    int cnt = min(gcursor[b], BBCAP);
    const unsigned* bk = &buckets[(size_t)b * BBCAP];
    for (int i = threadIdx.x; i < cnt; i += 256) {
        unsigned r = bk[i];
        int p = atomicAdd(&cur[r >> 17], 1);
        csr[p] = (int)(r & 0x1FFFFu);
    }
    __syncthreads();
    // fill pad region with dummy node N (h'[N] = 0, h2'[N] = 0)
    for (int i = threadIdx.x; i < NPB; i += 256) {
        int n = node0 + i;
        if (n < N) {
            int d = deg[n];
            int st = offsets[n] + d;
            int en = offsets[n] + ((d + 15) & ~15);
            for (int p = st; p < en; ++p) csr[p] = N;
        }
    }
}

// ---------------- W1 -> bf16 MFMA B-fragment order; zero h2' dummy rows ----------------
__global__ void k_prep_w1(const float* __restrict__ W1, unsigned short* __restrict__ w1s,
                          unsigned* __restrict__ h2p, int N) {
    // zero dummy row N in both h2' planes (16 uints each covers 10 + slack)
    if (blockIdx.x == 0 && threadIdx.x < 32) {
        size_t H2S = (size_t)(N + 1) * 10 + 16;
        int hh = threadIdx.x >> 4;
        int i = threadIdx.x & 15;
        h2p[(size_t)hh * H2S + (size_t)N * 10 + i] = 0;
    }
    int flat = blockIdx.x * 256 + threadIdx.x;   // 0..4095
    int kt = flat >> 9;
    int nt = (flat >> 6) & 7;
    int lane = flat & 63;
    int kbase = kt * 32 + ((lane >> 4) << 3);
    int n = nt * 16 + (lane & 15);
    unsigned short v[8];
    #pragma unroll
    for (int j = 0; j < 8; ++j) v[j] = f2bf(W1[(size_t)(kbase + j) * 128 + n]);
    unsigned short* d = &w1s[(size_t)flat * 8];
    *(short4*)(d)     = make_short4(v[0], v[1], v[2], v[3]);
    *(short4*)(d + 4) = make_short4(v[4], v[5], v[6], v[7]);
}

// ---------------- GEMM1: h'[planes] = isd*(x @ W1) , MFMA 16x16x32 ----------------
// h' stored as 2 column-planes: [half][(N+1) rows][32 uints] (cols 64*half..64*half+63)
__global__ __launch_bounds__(256) void k_gemm1(const float* __restrict__ X,
                                               const unsigned short* __restrict__ w1s,
                                               const float* __restrict__ isd,
                                               unsigned* __restrict__ Hp, int N) {
    __shared__ __align__(16) unsigned short smem[8192];
    unsigned short* sA = smem;
    unsigned short* sB = smem + 2048;
    int tid = threadIdx.x;
    int lane = tid & 63;
    int wave = tid >> 6;
    int wr = wave >> 1;
    int wc = wave & 1;
    int m0 = blockIdx.x * 64;
    size_t HS = (size_t)(N + 1) * 32;          // plane stride in uints

    floatx4 acc[2][4] = {};

    for (int kt = 0; kt < 8; ++kt) {
        #pragma unroll
        for (int i = 0; i < 2; ++i) {
            int f = tid * 2 + i;
            int row = f >> 3;
            int c4 = (f & 7) * 4;
            float4 v = make_float4(0.f, 0.f, 0.f, 0.f);
            int grow = m0 + row;
            if (grow < N) v = *(const float4*)&X[(size_t)grow * 256 + kt * 32 + c4];
            int mt = row >> 4;
            int flane = (row & 15) | ((c4 >> 3) << 4);
            int j0 = c4 & 7;
            unsigned short* d = &sA[(size_t)(mt * 64 + flane) * 8 + j0];
            *(short4*)d = make_short4(f2bf(v.x), f2bf(v.y), f2bf(v.z), f2bf(v.w));
        }
        {
            const float4* srcp = (const float4*)&w1s[(size_t)kt * 4096];
            float4* dstp = (float4*)sB;
            dstp[tid] = srcp[tid];
            dstp[tid + 256] = srcp[tid + 256];
        }
        __syncthreads();
        bf16x8 a[2], b[4];
        #pragma unroll
        for (int p = 0; p < 2; ++p)
            a[p] = *(const bf16x8*)&sA[(size_t)((wr * 2 + p) * 64 + lane) * 8];
        #pragma unroll
        for (int q = 0; q < 4; ++q)
            b[q] = *(const bf16x8*)&sB[(size_t)((wc * 4 + q) * 64 + lane) * 8];
        #pragma unroll
        for (int p = 0; p < 2; ++p)
            #pragma unroll
            for (int q = 0; q < 4; ++q)
                acc[p][q] = __builtin_amdgcn_mfma_f32_16x16x32_bf16(a[p], b[q], acc[p][q], 0, 0, 0);
        __syncthreads();
    }
    // per-row isd scale factors (8 rows per thread)
    float sc[2][4];
    #pragma unroll
    for (int p = 0; p < 2; ++p)
        #pragma unroll
        for (int r = 0; r < 4; ++r) {
            int g = m0 + wr * 32 + p * 16 + ((lane >> 4) << 2) + r;
            sc[p][r] = isd[g > N ? N : g];
        }
    #pragma unroll
    for (int p = 0; p < 2; ++p)
        #pragma unroll
        for (int q = 0; q < 4; ++q)
            #pragma unroll
            for (int r = 0; r < 4; ++r) {
                int rl = wr * 32 + p * 16 + ((lane >> 4) << 2) + r;
                int c = wc * 64 + q * 16 + (lane & 15);
                smem[rl * 128 + c] = f2bf(acc[p][q][r] * sc[p][r]);
            }
    __syncthreads();
    #pragma unroll
    for (int i = 0; i < 4; ++i) {
        int f = tid + i * 256;
        int row = f >> 4;
        int c8 = (f & 15) * 8;                 // bf16 col 0..120
        int grow = m0 + row;
        if (grow <= N) {                       // row N = zeros (dummy)
            int cu = c8 >> 1;                  // uint col 0..60
            int half = cu >> 5;
            int cin = cu & 31;                 // 0,4,...,28
            *(float4*)&Hp[(size_t)half * HS + (size_t)grow * 32 + cin] =
                *(const float4*)&smem[row * 128 + c8];
        }
    }
}

// ---------------- agg1: h1(bf16) = relu(b1 + isdn * sum h'[src]) , C=128 ----------------
// R2: column-half per XCD group (blockIdx%8>>2). 2 nodes/wave, 2 edges/load-instr.
__global__ __launch_bounds__(256) void k_agg1(const unsigned* __restrict__ Hp,
                                              const int* __restrict__ csr,
                                              const float* __restrict__ isd,
                                              const int* __restrict__ offsets,
                                              const int* __restrict__ deg,
                                              const float* __restrict__ b1,
                                              unsigned* __restrict__ H1u, int N) {
    int b = blockIdx.x;
    int xcd = b & 7;
    int half = xcd >> 2;                          // XCDs 0-3 -> cols 0-63, 4-7 -> 64-127
    int hb = (b >> 3) * 4 + (xcd & 3);            // block index within half
    int wave = threadIdx.x >> 6;
    int lane = threadIdx.x & 63;
    int n0 = __builtin_amdgcn_readfirstlane(hb * 8 + wave * 2);
    if (n0 >= N) return;
    size_t HS = (size_t)(N + 1) * 32;
    const unsigned* P = Hp + (size_t)half * HS;
    int sub = lane >> 5;                          // edge parity
    int c = lane & 31;                            // packed col within half
    int startk[2], nbk[2];
    float a0[2] = {0.f, 0.f}, a1[2] = {0.f, 0.f};
    int maxnb = 0;
    #pragma unroll
    for (int k = 0; k < 2; ++k) {
        int n = n0 + k;
        bool v = (n < N);
        startk[k] = v ? offsets[n] : 0;
        nbk[k] = v ? (deg[n] + 15) >> 4 : 0;
        maxnb = max(maxnb, nbk[k]);
    }
    for (int ib = 0; ib < maxnb; ++ib) {
        unsigned p[2][8];
        #pragma unroll
        for (int k = 0; k < 2; ++k) {
            if (ib < nbk[k]) {
                int b0 = startk[k] + ib * 16;
                int s[8];
                #pragma unroll
                for (int j = 0; j < 8; ++j) s[j] = csr[b0 + (j << 1) + sub];
                #pragma unroll
                for (int j = 0; j < 8; ++j) p[k][j] = P[(size_t)s[j] * 32 + c];
            }
        }
        #pragma unroll
        for (int k = 0; k < 2; ++k) {
            if (ib < nbk[k]) {
                #pragma unroll
                for (int j = 0; j < 8; ++j) {
                    a0[k] += bflo(p[k][j]);
                    a1[k] += bfhi(p[k][j]);
                }
            }
        }
    }
    #pragma unroll
    for (int k = 0; k < 2; ++k) {
        a0[k] += __shfl(a0[k], lane + 32);
        a1[k] += __shfl(a1[k], lane + 32);
    }
    if (lane < 32) {
        int col0 = 2 * (half * 32 + lane);
        float bl = b1[col0];
        float bh = b1[col0 + 1];
        #pragma unroll
        for (int k = 0; k < 2; ++k) {
            int n = n0 + k;
            if (n < N) {
                float isdn = isd[n];
                float r0 = fmaxf(fmaf(isdn, a0[k], bl), 0.f);
                float r1 = fmaxf(fmaf(isdn, a1[k], bh), 0.f);
                H1u[(size_t)n * 64 + half * 32 + lane] =
                    (unsigned)f2bf(r0) | ((unsigned)f2bf(r1) << 16);
            }
        }
    }
}

// ---------------- GEMM2: h2'[planes] = isd*(h1 @ W2) ----------------
// h2' stored as 2 column-planes: [half][(N+1) rows][10 uints] (cols 20*half..20*half+19)
__global__ __launch_bounds__(256) void k_gemm2(const unsigned short* __restrict__ H1,
                                               const float* __restrict__ W2,
                                               const float* __restrict__ isd,
                                               unsigned* __restrict__ H2p, int N) {
    __shared__ float sH[64][132];
    __shared__ float sW[128 * 40];
    int tid = threadIdx.x;
    int block_row = blockIdx.x * 64;
    size_t H2S = (size_t)(N + 1) * 10 + 16;
    for (int i = tid; i < 64 * 16; i += 256) {
        int r = i >> 4;
        int c8 = (i & 15) * 8;
        int grow = block_row + r;
        uint4 v = make_uint4(0, 0, 0, 0);
        if (grow < N) v = *(const uint4*)&H1[(size_t)grow * 128 + c8];
        float* d = &sH[r][c8];
        d[0] = bflo(v.x); d[1] = bfhi(v.x);
        d[2] = bflo(v.y); d[3] = bfhi(v.y);
        d[4] = bflo(v.z); d[5] = bfhi(v.z);
        d[6] = bflo(v.w); d[7] = bfhi(v.w);
    }
    for (int i = tid; i < 1280; i += 256)
        *(float4*)&sW[i * 4] = *(const float4*)&W2[(size_t)i * 4];
    __syncthreads();

    int row = tid >> 2;
    int c0 = (tid & 3) * 10;
    float acc[10] = {};
    for (int k = 0; k < 128; ++k) {
        float hv = sH[row][k];
        #pragma unroll
        for (int j = 0; j < 5; ++j) {
            float2 wv = *(const float2*)&sW[k * 40 + c0 + 2 * j];
            acc[2 * j]     = fmaf(hv, wv.x, acc[2 * j]);
            acc[2 * j + 1] = fmaf(hv, wv.y, acc[2 * j + 1]);
        }
    }
    int grow = block_row + row;
    if (grow < N) {
        float scn = isd[grow];
        int half = c0 >= 20;
        int c0h = c0 - half * 20;              // 0 or 10
        unsigned* o = &H2p[(size_t)half * H2S + (size_t)grow * 10 + (c0h >> 1)];
        #pragma unroll
        for (int j = 0; j < 5; ++j)
            o[j] = (unsigned)f2bf(acc[2 * j] * scn) |
                   ((unsigned)f2bf(acc[2 * j + 1] * scn) << 16);
    }
}

// ---------------- agg2: out = b2 + isdn * sum h2'[src] , C=40 ----------------
// R2: column-half per XCD group (4MB plane = L2-resident). 4 nodes/wave, 4 edges/instr,
// c=lane&15 with c<10 predicated loads (40B/edge requests).
__global__ __launch_bounds__(256) void k_agg2(const unsigned* __restrict__ H2p,
                                              const int* __restrict__ csr,
                                              const float* __restrict__ isd,
                                              const int* __restrict__ offsets,
                                              const int* __restrict__ deg,
                                              const float* __restrict__ b2,
                                              float* __restrict__ out, int N) {
    int b = blockIdx.x;
    int xcd = b & 7;
    int half = xcd >> 2;
    int hb = (b >> 3) * 4 + (xcd & 3);
    int wave = threadIdx.x >> 6;
    int lane = threadIdx.x & 63;
    int n0 = __builtin_amdgcn_readfirstlane(hb * 16 + wave * 4);
    if (n0 >= N) return;
    size_t H2S = (size_t)(N + 1) * 10 + 16;
    const unsigned* P = H2p + (size_t)half * H2S;
    int sub = lane >> 4;                          // edge 0..3 within quad
    int c = lane & 15;                            // active c<10
    int startk[4], nbk[4];
    float a0[4] = {0.f, 0.f, 0.f, 0.f};
    float a1[4] = {0.f, 0.f, 0.f, 0.f};
    int maxnb = 0;
    #pragma unroll
    for (int k = 0; k < 4; ++k) {
        int n = n0 + k;
        bool v = (n < N);
        startk[k] = v ? offsets[n] : 0;
        nbk[k] = v ? (deg[n] + 15) >> 4 : 0;
        maxnb = max(maxnb, nbk[k]);
    }
    for (int ib = 0; ib < maxnb; ++ib) {
        unsigned q[4][4];
        #pragma unroll
        for (int k = 0; k < 4; ++k) {
            if (ib < nbk[k]) {
                int b0 = startk[k] + ib * 16;
                int s[4];
                #pragma unroll
                for (int j = 0; j < 4; ++j) s[j] = csr[b0 + (j << 2) + sub];
                #pragma unroll
                for (int j = 0; j < 4; ++j)
                    q[k][j] = (c < 10) ? P[(size_t)s[j] * 10 + c] : 0u;
            }
        }
        #pragma unroll
        for (int k = 0; k < 4; ++k) {
            if (ib < nbk[k]) {
                #pragma unroll
                for (int j = 0; j < 4; ++j) {
                    a0[k] += bflo(q[k][j]);
                    a1[k] += bfhi(q[k][j]);
                }
            }
        }
    }
    #pragma unroll
    for (int k = 0; k < 4; ++k) {
        a0[k] += __shfl(a0[k], lane + 32);
        a1[k] += __shfl(a1[k], lane + 32);
        a0[k] += __shfl(a0[k], lane + 16);
        a1[k] += __shfl(a1[k], lane + 16);
    }
    if (lane < 10) {
        int col0 = half * 20 + 2 * lane;
        float bl = b2[col0];
        float bh = b2[col0 + 1];
        #pragma unroll
        for (int k = 0; k < 4; ++k) {
            int n = n0 + k;
            if (n < N) {
                float isdn = isd[n];
                *(float2*)&out[(size_t)n * 40 + col0] =
                    make_float2(fmaf(isdn, a0[k], bl), fmaf(isdn, a1[k], bh));
            }
        }
    }
}

extern "C" void kernel_launch(void* const* d_in, const int* in_sizes, int n_in,
                              void* d_out, int out_size, void* d_ws, size_t ws_size,
                              hipStream_t stream) {
    const float* x  = (const float*)d_in[0];
    const int*  src = (const int*)d_in[1];
    const int*  dst = (const int*)d_in[2];
    const float* W1 = (const float*)d_in[3];
    const float* b1 = (const float*)d_in[4];
    const float* W2 = (const float*)d_in[5];
    const float* b2 = (const float*)d_in[6];
    float* out = (float*)d_out;

    const int N = in_sizes[0] / 256;   // 100000
    const int E = in_sizes[1];         // 1600000

    char* w = (char*)d_ws;
    auto alloc = [&](size_t bytes) -> void* {
        void* p = (void*)w;
        w += (bytes + 15) & ~(size_t)15;
        return p;
    };
    size_t HS  = (size_t)(N + 1) * 32;        // h' plane stride (uints)
    size_t H2S = (size_t)(N + 1) * 10 + 16;   // h2' plane stride (uints)
    int*      gcursor = (int*)alloc(256 * 4);                 // zeroed
    int*      counter = (int*)alloc(16);                      // zeroed
    int*      deg     = (int*)alloc((size_t)N * 4);
    float*    isd     = (float*)alloc((size_t)(N + 1) * 4);
    int*      offsets = (int*)alloc((size_t)(N + 1) * 4);
    unsigned* buckets = (unsigned*)alloc((size_t)NBUCK * BBCAP * 4);
    int*      csr     = (int*)alloc((size_t)(E + 16 * (size_t)N) * 4);
    unsigned short* w1s = (unsigned short*)alloc(32768 * 2);
    unsigned* h  = (unsigned*)alloc(2 * HS * 4);              // h' planes
    unsigned short* h1 = (unsigned short*)alloc((size_t)N * 128 * 2);
    unsigned* h2 = (unsigned*)alloc(2 * H2S * 4);             // h2' planes

    hipMemsetAsync(gcursor, 0, 256 * 4 + 16, stream);

    int nchunk = (E + CHUNK - 1) / CHUNK;   // 392
    k_part<<<nchunk, 256, 0, stream>>>(src, dst, gcursor, buckets, E);
    k_count<<<NBUCK, 256, 0, stream>>>(buckets, gcursor, deg, N);
    k_isd_offsets<<<(N + 256) / 256, 256, 0, stream>>>(deg, isd, offsets, counter, N);
    k_place<<<NBUCK, 256, 0, stream>>>(buckets, gcursor, offsets, deg, csr, N);
    k_prep_w1<<<16, 256, 0, stream>>>(W1, w1s, h2, N);
    k_gemm1<<<(N + 63) / 64, 256, 0, stream>>>(x, w1s, isd, h, N);
    // agg1: 8 nodes/block/half; blocks-per-half multiple of 4 for the %8 interleave
    int hb1 = (((N + 7) / 8) + 3) & ~3;     // 12500
    k_agg1<<<2 * hb1, 256, 0, stream>>>(h, csr, isd, offsets, deg, b1, (unsigned*)h1, N);
    k_gemm2<<<(N + 63) / 64, 256, 0, stream>>>(h1, W2, isd, h2, N);
    // agg2: 16 nodes/block/half
    int hb2 = (((N + 15) / 16) + 3) & ~3;   // 6252
    k_agg2<<<2 * hb2, 256, 0, stream>>>(h2, csr, isd, offsets, deg, b2, out, N);
}

// Round 4
// 432.770 us; speedup vs baseline: 1.0245x; 1.0245x over previous
//
#include <hip/hip_runtime.h>
#include <hip/hip_bf16.h>

// GCN 2-layer. CSR via block-local radix partition, 16-padded lists (dummy node N).
// h' = isd*(x@W1), h2' = isd*(h1@W2) pre-scaled at producer => agg loops are pure
// {index load, row gather, unpack, add}. Intermediates bf16. GEMM1 = bf16 MFMA.
// R4: agg kernels = verified R0 forms (agg1 fill-limited at ~3.4 TB/s L2-miss path).
//     Pipeline compaction: k_count removed (deg via global atomics in k_part);
//     prep_w1 fused into part launch; place(+isd+offsets scan) fused ∥ gemm1
//     (gemm1 derives its scale from deg directly). 10 dispatches -> 6.

#define CHUNK   4096              // edges per partition block (392 blocks)
#define NPB     512               // nodes per bucket (dst >> 9)
#define NBUCK   196               // ceil(100000/512)
#define BBCAP   9216              // bucket capacity (mean 8163, +11 sigma)

typedef __bf16 bf16x8 __attribute__((ext_vector_type(8)));
typedef float floatx4 __attribute__((ext_vector_type(4)));

__device__ inline unsigned short f2bf(float f) {      // RNE fp32->bf16
    unsigned u = __float_as_uint(f);
    u += 0x7FFF + ((u >> 16) & 1);
    return (unsigned short)(u >> 16);
}
__device__ inline float bflo(unsigned p) { return __uint_as_float(p << 16); }
__device__ inline float bfhi(unsigned p) { return __uint_as_float(p & 0xFFFF0000u); }

// ---------------- F1: radix partition (+deg atomics)  ||  W1 prep ----------------
// part blocks [0,nchunk); prep blocks [nchunk, nchunk+16)
__global__ __launch_bounds__(256) void k_f1(const int* __restrict__ src,
                                            const int* __restrict__ dst,
                                            int* __restrict__ gcursor,
                                            unsigned* __restrict__ buckets,
                                            int* __restrict__ deg,
                                            int E, int nchunk,
                                            const float* __restrict__ W1,
                                            unsigned short* __restrict__ w1s,
                                            unsigned* __restrict__ h2z) {
    int t = threadIdx.x;
    if ((int)blockIdx.x >= nchunk) {
        // ---- prep_w1: W1 -> bf16 MFMA B-fragment order; zero h2' dummy row ----
        int pb = blockIdx.x - nchunk;
        if (pb == 0 && t < 36) h2z[t] = 0;            // row N + slack
        int flat = pb * 256 + t;                      // 0..4095
        int kt = flat >> 9;
        int nt = (flat >> 6) & 7;
        int lane = flat & 63;
        int kbase = kt * 32 + ((lane >> 4) << 3);
        int n = nt * 16 + (lane & 15);
        unsigned short v[8];
        #pragma unroll
        for (int j = 0; j < 8; ++j) v[j] = f2bf(W1[(size_t)(kbase + j) * 128 + n]);
        unsigned short* d = &w1s[(size_t)flat * 8];
        *(short4*)(d)     = make_short4(v[0], v[1], v[2], v[3]);
        *(short4*)(d + 4) = make_short4(v[4], v[5], v[6], v[7]);
        return;
    }
    // ---- partition: rec = src (17b) | (dst&511)<<17, bucket = dst>>9 ----
    __shared__ unsigned srec[CHUNK];          // 16 KB
    __shared__ unsigned char sb8[CHUNK];      // 4 KB
    __shared__ int hist[NBUCK];
    __shared__ int lbase[NBUCK];
    __shared__ int gbase[NBUCK];
    __shared__ int scanbuf[256];
    int base = blockIdx.x * CHUNK;
    int cnt = min(CHUNK, E - base);           // multiple of 4
    for (int i = t; i < NBUCK; i += 256) hist[i] = 0;
    __syncthreads();

    unsigned rec[16];
    unsigned br[16];                          // b (8b) | rank<<8
    bool valid[4];
    #pragma unroll
    for (int k = 0; k < 4; ++k) {
        int e0 = k * 1024 + t * 4;
        valid[k] = (e0 < cnt);
        if (valid[k]) {
            int4 s4 = *(const int4*)&src[base + e0];
            int4 d4 = *(const int4*)&dst[base + e0];
            int ss[4] = {s4.x, s4.y, s4.z, s4.w};
            int dd[4] = {d4.x, d4.y, d4.z, d4.w};
            #pragma unroll
            for (int j = 0; j < 4; ++j) {
                int b = dd[j] >> 9;
                int r = atomicAdd(&hist[b], 1);           // LDS atomic
                atomicAdd(&deg[dd[j]], 1);                // global degree histogram
                rec[k * 4 + j] = (unsigned)ss[j] | ((unsigned)(dd[j] & 511) << 17);
                br[k * 4 + j] = (unsigned)b | ((unsigned)r << 8);
            }
        }
    }
    __syncthreads();
    // inclusive Hillis-Steele scan over 256 (NBUCK padded)
    scanbuf[t] = (t < NBUCK) ? hist[t] : 0;
    __syncthreads();
    for (int s = 1; s < 256; s <<= 1) {
        int v = (t >= s) ? scanbuf[t - s] : 0;
        __syncthreads();
        scanbuf[t] += v;
        __syncthreads();
    }
    if (t < NBUCK) {
        lbase[t] = scanbuf[t] - hist[t];                  // exclusive base
        gbase[t] = atomicAdd(&gcursor[t], hist[t]);       // per-bucket global atomic
    }
    __syncthreads();
    // reorder into LDS, grouped by bucket
    #pragma unroll
    for (int k = 0; k < 4; ++k) {
        if (valid[k]) {
            #pragma unroll
            for (int j = 0; j < 4; ++j) {
                unsigned b = br[k * 4 + j] & 255u;
                unsigned r = br[k * 4 + j] >> 8;
                int p = lbase[b] + (int)r;
                srec[p] = rec[k * 4 + j];
                sb8[p] = (unsigned char)b;
            }
        }
    }
    __syncthreads();
    // dense flat write
    for (int i = t; i < cnt; i += 256) {
        int b = sb8[i];
        int pos = gbase[b] + (i - lbase[b]);
        if (pos < BBCAP) buckets[(size_t)b * BBCAP + pos] = srec[i];
    }
}

// ---------------- F2: place(+isd+offsets via in-block scan)  ||  GEMM1 ----------------
// place blocks [0,NBUCK); gemm1 blocks [NBUCK, NBUCK+G1). gemm1 scales by rsqrt(deg)
// directly (no dependence on the isd array being written concurrently by place).
__global__ __launch_bounds__(256) void k_f2(const unsigned* __restrict__ buckets,
                                            const int* __restrict__ gcursor,
                                            const int* __restrict__ deg,
                                            int* __restrict__ counter,
                                            int* __restrict__ offsets,
                                            float* __restrict__ isd,
                                            int* __restrict__ csr,
                                            const float* __restrict__ X,
                                            const unsigned short* __restrict__ w1s,
                                            unsigned short* __restrict__ H, int N) {
    __shared__ __align__(16) unsigned char SH[16384];
    int tid = threadIdx.x;
    if ((int)blockIdx.x < NBUCK) {
        // ---- place: per-bucket padded prefix scan -> offsets/isd, then CSR fill ----
        int* s_off = (int*)SH;                 // [512] absolute start offsets
        int* s_deg = (int*)(SH + 2048);        // [512]
        int* cur   = (int*)(SH + 4096);        // [512] live cursors
        int* sb    = (int*)(SH + 6144);        // [256] scan buffer
        int* sbase = (int*)(SH + 7168);        // [1]
        int b = blockIdx.x;
        int node0 = b << 9;
        int i0 = tid * 2;
        int na = node0 + i0, nb = node0 + i0 + 1;
        int da = (na < N) ? deg[na] : 0;
        int db = (nb < N) ? deg[nb] : 0;
        int dpa = (da + 15) & ~15, dpb = (db + 15) & ~15;
        sb[tid] = dpa + dpb;
        __syncthreads();
        for (int s = 1; s < 256; s <<= 1) {
            int v = (tid >= s) ? sb[tid - s] : 0;
            __syncthreads();
            sb[tid] += v;
            __syncthreads();
        }
        int excl = sb[tid] - (dpa + dpb);
        if (tid == 0) *sbase = atomicAdd(counter, sb[255]);
        if (b == 0 && tid == 1) isd[N] = 0.f;          // dummy node
        __syncthreads();
        int offa = *sbase + excl;
        int offb = offa + dpa;
        if (na < N) { offsets[na] = offa; isd[na] = (da > 0) ? rsqrtf((float)da) : 0.f; }
        if (nb < N) { offsets[nb] = offb; isd[nb] = (db > 0) ? rsqrtf((float)db) : 0.f; }
        s_off[i0] = offa; s_off[i0 + 1] = offb;
        s_deg[i0] = da;   s_deg[i0 + 1] = db;
        cur[i0] = offa;   cur[i0 + 1] = offb;
        __syncthreads();
        int cnt = min(gcursor[b], BBCAP);
        const unsigned* bk = &buckets[(size_t)b * BBCAP];
        for (int i = tid; i < cnt; i += 256) {
            unsigned r = bk[i];
            int p = atomicAdd(&cur[r >> 17], 1);
            csr[p] = (int)(r & 0x1FFFFu);
        }
        __syncthreads();
        // fill pad region with dummy node N (h'[N] = 0, h2'[N] = 0)
        for (int i = tid; i < NPB; i += 256) {
            int n = node0 + i;
            if (n < N) {
                int d = s_deg[i];
                int st = s_off[i] + d;
                int en = s_off[i] + ((d + 15) & ~15);
                for (int p = st; p < en; ++p) csr[p] = N;
            }
        }
        return;
    }
    // ---- GEMM1: h'[N+1,128](bf16) = rsqrt(deg)*(x @ W1), MFMA 16x16x32 ----
    unsigned short* smem = (unsigned short*)SH;
    unsigned short* sA = smem;
    unsigned short* sB = smem + 2048;
    int lane = tid & 63;
    int wave = tid >> 6;
    int wr = wave >> 1;
    int wc = wave & 1;
    int m0 = (blockIdx.x - NBUCK) * 64;

    floatx4 acc[2][4] = {};

    for (int kt = 0; kt < 8; ++kt) {
        #pragma unroll
        for (int i = 0; i < 2; ++i) {
            int f = tid * 2 + i;
            int row = f >> 3;
            int c4 = (f & 7) * 4;
            float4 v = make_float4(0.f, 0.f, 0.f, 0.f);
            int grow = m0 + row;
            if (grow < N) v = *(const float4*)&X[(size_t)grow * 256 + kt * 32 + c4];
            int mt = row >> 4;
            int flane = (row & 15) | ((c4 >> 3) << 4);
            int j0 = c4 & 7;
            unsigned short* d = &sA[(size_t)(mt * 64 + flane) * 8 + j0];
            *(short4*)d = make_short4(f2bf(v.x), f2bf(v.y), f2bf(v.z), f2bf(v.w));
        }
        {
            const float4* srcp = (const float4*)&w1s[(size_t)kt * 4096];
            float4* dstp = (float4*)sB;
            dstp[tid] = srcp[tid];
            dstp[tid + 256] = srcp[tid + 256];
        }
        __syncthreads();
        bf16x8 a[2], b[4];
        #pragma unroll
        for (int p = 0; p < 2; ++p)
            a[p] = *(const bf16x8*)&sA[(size_t)((wr * 2 + p) * 64 + lane) * 8];
        #pragma unroll
        for (int q = 0; q < 4; ++q)
            b[q] = *(const bf16x8*)&sB[(size_t)((wc * 4 + q) * 64 + lane) * 8];
        #pragma unroll
        for (int p = 0; p < 2; ++p)
            #pragma unroll
            for (int q = 0; q < 4; ++q)
                acc[p][q] = __builtin_amdgcn_mfma_f32_16x16x32_bf16(a[p], b[q], acc[p][q], 0, 0, 0);
        __syncthreads();
    }
    // per-row scale = rsqrt(deg) (8 rows per thread)
    float sc[2][4];
    #pragma unroll
    for (int p = 0; p < 2; ++p)
        #pragma unroll
        for (int r = 0; r < 4; ++r) {
            int g = m0 + wr * 32 + p * 16 + ((lane >> 4) << 2) + r;
            float s = 0.f;
            if (g < N) {
                int dv = deg[g];
                s = (dv > 0) ? rsqrtf((float)dv) : 0.f;
            }
            sc[p][r] = s;
        }
    #pragma unroll
    for (int p = 0; p < 2; ++p)
        #pragma unroll
        for (int q = 0; q < 4; ++q)
            #pragma unroll
            for (int r = 0; r < 4; ++r) {
                int rl = wr * 32 + p * 16 + ((lane >> 4) << 2) + r;
                int c = wc * 64 + q * 16 + (lane & 15);
                smem[rl * 128 + c] = f2bf(acc[p][q][r] * sc[p][r]);
            }
    __syncthreads();
    #pragma unroll
    for (int i = 0; i < 4; ++i) {
        int f = tid + i * 256;
        int row = f >> 4;
        int c8 = (f & 15) * 8;
        int grow = m0 + row;
        if (grow <= N)   // row N = zeros (dummy)
            *(float4*)&H[(size_t)grow * 128 + c8] = *(const float4*)&smem[row * 128 + c8];
    }
}

// ---------------- agg1: h1(bf16) = relu(b1 + isdn * sum h'[src]) , C=128 ----------------
__global__ __launch_bounds__(256) void k_agg1(const unsigned* __restrict__ Hu,
                                              const int* __restrict__ csr,
                                              const float* __restrict__ isd,
                                              const int* __restrict__ offsets,
                                              const int* __restrict__ deg,
                                              const float* __restrict__ b1,
                                              unsigned* __restrict__ H1u, int N) {
    int node = __builtin_amdgcn_readfirstlane((blockIdx.x * blockDim.x + threadIdx.x) >> 6);
    int lane = threadIdx.x & 63;
    if (node >= N) return;
    int start = offsets[node];
    int nb = (deg[node] + 15) >> 4;
    float isdn = isd[node];
    float acc0 = 0.f, acc1 = 0.f;
    for (int ib = 0; ib < nb; ++ib) {
        int b0 = start + ib * 16;
        int s[16];
        #pragma unroll
        for (int j = 0; j < 16; ++j) s[j] = csr[b0 + j];        // scalar loads
        unsigned p[16];
        #pragma unroll
        for (int j = 0; j < 16; ++j) p[j] = Hu[(size_t)s[j] * 64 + lane];
        #pragma unroll
        for (int j = 0; j < 16; ++j) {
            acc0 += bflo(p[j]);
            acc1 += bfhi(p[j]);
        }
    }
    float r0 = fmaxf(fmaf(isdn, acc0, b1[2 * lane]), 0.f);
    float r1 = fmaxf(fmaf(isdn, acc1, b1[2 * lane + 1]), 0.f);
    H1u[(size_t)node * 64 + lane] = (unsigned)f2bf(r0) | ((unsigned)f2bf(r1) << 16);
}

// ---------------- GEMM2: h2'[N+1,40](bf16) = isd*(h1 @ W2) ----------------
__global__ __launch_bounds__(256) void k_gemm2(const unsigned short* __restrict__ H1,
                                               const float* __restrict__ W2,
                                               const float* __restrict__ isd,
                                               unsigned short* __restrict__ H2, int N) {
    __shared__ float sH[64][132];
    __shared__ float sW[128 * 40];
    int tid = threadIdx.x;
    int block_row = blockIdx.x * 64;
    for (int i = tid; i < 64 * 16; i += 256) {
        int r = i >> 4;
        int c8 = (i & 15) * 8;
        int grow = block_row + r;
        uint4 v = make_uint4(0, 0, 0, 0);
        if (grow < N) v = *(const uint4*)&H1[(size_t)grow * 128 + c8];
        float* d = &sH[r][c8];
        d[0] = bflo(v.x); d[1] = bfhi(v.x);
        d[2] = bflo(v.y); d[3] = bfhi(v.y);
        d[4] = bflo(v.z); d[5] = bfhi(v.z);
        d[6] = bflo(v.w); d[7] = bfhi(v.w);
    }
    for (int i = tid; i < 1280; i += 256)
        *(float4*)&sW[i * 4] = *(const float4*)&W2[(size_t)i * 4];
    __syncthreads();

    int row = tid >> 2;
    int c0 = (tid & 3) * 10;
    float acc[10] = {};
    for (int k = 0; k < 128; ++k) {
        float hv = sH[row][k];
        #pragma unroll
        for (int j = 0; j < 5; ++j) {
            float2 wv = *(const float2*)&sW[k * 40 + c0 + 2 * j];
            acc[2 * j]     = fmaf(hv, wv.x, acc[2 * j]);
            acc[2 * j + 1] = fmaf(hv, wv.y, acc[2 * j + 1]);
        }
    }
    int grow = block_row + row;
    if (grow < N) {
        float scn = isd[grow];
        unsigned* o = (unsigned*)&H2[(size_t)grow * 40 + c0];
        #pragma unroll
        for (int j = 0; j < 5; ++j)
            o[j] = (unsigned)f2bf(acc[2 * j] * scn) |
                   ((unsigned)f2bf(acc[2 * j + 1] * scn) << 16);
    }
}

// ---------------- agg2: out = b2 + isdn * sum h2'[src] , C=40 ----------------
// sub = lane>>5 (2 edges/instr), c = lane&31 (c<20 active); 8-deep MLP, unpredicated
__global__ __launch_bounds__(256) void k_agg2(const unsigned* __restrict__ Hu2,
                                              const int* __restrict__ csr,
                                              const float* __restrict__ isd,
                                              const int* __restrict__ offsets,
                                              const int* __restrict__ deg,
                                              const float* __restrict__ b2,
                                              float* __restrict__ out, int N) {
    int node = __builtin_amdgcn_readfirstlane((blockIdx.x * blockDim.x + threadIdx.x) >> 6);
    int lane = threadIdx.x & 63;
    if (node >= N) return;
    int start = offsets[node];
    int nb = (deg[node] + 15) >> 4;
    float isdn = isd[node];
    int sub = lane >> 5;       // 0/1
    int c = lane & 31;         // active c<20; c in [20,32) reads slack (finite, unused)
    float acc0 = 0.f, acc1 = 0.f;
    for (int ib = 0; ib < nb; ++ib) {
        int b0 = start + ib * 16;
        #pragma unroll
        for (int j = 0; j < 8; ++j) {
            int s = csr[b0 + (j << 1) + sub];
            unsigned q = Hu2[(size_t)s * 20 + c];
            acc0 += bflo(q);
            acc1 += bfhi(q);
        }
    }
    acc0 += __shfl(acc0, lane + 32);
    acc1 += __shfl(acc1, lane + 32);
    if (lane < 20)
        *(float2*)&out[(size_t)node * 40 + 2 * lane] =
            make_float2(fmaf(isdn, acc0, b2[2 * lane]), fmaf(isdn, acc1, b2[2 * lane + 1]));
}

extern "C" void kernel_launch(void* const* d_in, const int* in_sizes, int n_in,
                              void* d_out, int out_size, void* d_ws, size_t ws_size,
                              hipStream_t stream) {
    const float* x  = (const float*)d_in[0];
    const int*  src = (const int*)d_in[1];
    const int*  dst = (const int*)d_in[2];
    const float* W1 = (const float*)d_in[3];
    const float* b1 = (const float*)d_in[4];
    const float* W2 = (const float*)d_in[5];
    const float* b2 = (const float*)d_in[6];
    float* out = (float*)d_out;

    const int N = in_sizes[0] / 256;   // 100000
    const int E = in_sizes[1];         // 1600000

    char* w = (char*)d_ws;
    auto alloc = [&](size_t bytes) -> void* {
        void* p = (void*)w;
        w += (bytes + 15) & ~(size_t)15;
        return p;
    };
    int*      gcursor = (int*)alloc(256 * 4);                 // zeroed
    int*      counter = (int*)alloc(16);                      // zeroed
    int*      deg     = (int*)alloc((size_t)N * 4);           // zeroed (atomic histogram)
    float*    isd     = (float*)alloc((size_t)(N + 1) * 4);
    int*      offsets = (int*)alloc((size_t)(N + 1) * 4);
    unsigned* buckets = (unsigned*)alloc((size_t)NBUCK * BBCAP * 4);
    int*      csr     = (int*)alloc((size_t)(E + 16 * (size_t)N) * 4);
    unsigned short* w1s = (unsigned short*)alloc(32768 * 2);
    unsigned short* h   = (unsigned short*)alloc((size_t)(N + 1) * 128 * 2);  // h'
    unsigned short* h1  = (unsigned short*)alloc((size_t)N * 128 * 2);
    unsigned short* h2  = (unsigned short*)alloc(((size_t)(N + 1) * 20 + 16) * 4);  // h2'

    // zero gcursor + counter + deg (contiguous in the workspace)
    hipMemsetAsync(gcursor, 0, 256 * 4 + 16 + (size_t)N * 4, stream);

    int nchunk = (E + CHUNK - 1) / CHUNK;   // 392
    int G1 = (N + 63) / 64;                 // 1563
    k_f1<<<nchunk + 16, 256, 0, stream>>>(src, dst, gcursor, buckets, deg, E, nchunk,
                                          W1, w1s, (unsigned*)h2 + (size_t)N * 20);
    k_f2<<<NBUCK + G1, 256, 0, stream>>>(buckets, gcursor, deg, counter, offsets, isd,
                                         csr, x, w1s, h, N);
    k_agg1<<<(N + 3) / 4, 256, 0, stream>>>((const unsigned*)h, csr, isd, offsets, deg,
                                            b1, (unsigned*)h1, N);
    k_gemm2<<<G1, 256, 0, stream>>>(h1, W2, isd, h2, N);
    k_agg2<<<(N + 3) / 4, 256, 0, stream>>>((const unsigned*)h2, csr, isd, offsets, deg,
                                            b2, out, N);
}

// Round 5
// 374.941 us; speedup vs baseline: 1.1825x; 1.1542x over previous
//
#include <hip/hip_runtime.h>
#include <hip/hip_bf16.h>

// GCN 2-layer. CSR via block-local radix partition, 16-padded lists (dummy node N).
// R5: h' = UNSCALED x@W1 (bf16); agg1 applies isd[src] per edge via scalar loads
//     (wave-uniform indices -> s_load + v_fmac, zero extra VALU). This removes
//     gemm1's deg dependence so deg/isd/offsets are computed entirely inside the
//     f2 place path (block-local LDS histogram of its own bucket) -- the R4 global
//     deg atomics (the 433us regression) are gone. h2' = isd*(h1@W2) stays
//     producer-scaled (no race: gemm2 runs after f2). 5 dispatches.

#define CHUNK   4096              // edges per partition block (392 blocks)
#define NPB     512               // nodes per bucket (dst >> 9)
#define NBUCK   196               // ceil(100000/512)
#define BBCAP   9216              // bucket capacity (mean 8163, +11 sigma)

typedef __bf16 bf16x8 __attribute__((ext_vector_type(8)));
typedef float floatx4 __attribute__((ext_vector_type(4)));

__device__ inline unsigned short f2bf(float f) {      // RNE fp32->bf16
    unsigned u = __float_as_uint(f);
    u += 0x7FFF + ((u >> 16) & 1);
    return (unsigned short)(u >> 16);
}
__device__ inline float bflo(unsigned p) { return __uint_as_float(p << 16); }
__device__ inline float bfhi(unsigned p) { return __uint_as_float(p & 0xFFFF0000u); }

// ---------------- F1: radix partition  ||  W1 prep ----------------
// part blocks [0,nchunk); prep blocks [nchunk, nchunk+16)
__global__ __launch_bounds__(256) void k_f1(const int* __restrict__ src,
                                            const int* __restrict__ dst,
                                            int* __restrict__ gcursor,
                                            unsigned* __restrict__ buckets,
                                            int E, int nchunk,
                                            const float* __restrict__ W1,
                                            unsigned short* __restrict__ w1s,
                                            unsigned* __restrict__ h2z) {
    int t = threadIdx.x;
    if ((int)blockIdx.x >= nchunk) {
        // ---- prep_w1: W1 -> bf16 MFMA B-fragment order; zero h2' dummy row ----
        int pb = blockIdx.x - nchunk;
        if (pb == 0 && t < 36) h2z[t] = 0;            // row N + slack
        int flat = pb * 256 + t;                      // 0..4095
        int kt = flat >> 9;
        int nt = (flat >> 6) & 7;
        int lane = flat & 63;
        int kbase = kt * 32 + ((lane >> 4) << 3);
        int n = nt * 16 + (lane & 15);
        unsigned short v[8];
        #pragma unroll
        for (int j = 0; j < 8; ++j) v[j] = f2bf(W1[(size_t)(kbase + j) * 128 + n]);
        unsigned short* d = &w1s[(size_t)flat * 8];
        *(short4*)(d)     = make_short4(v[0], v[1], v[2], v[3]);
        *(short4*)(d + 4) = make_short4(v[4], v[5], v[6], v[7]);
        return;
    }
    // ---- partition: rec = src (17b) | (dst&511)<<17, bucket = dst>>9 ----
    __shared__ unsigned srec[CHUNK];          // 16 KB
    __shared__ unsigned char sb8[CHUNK];      // 4 KB
    __shared__ int hist[NBUCK];
    __shared__ int lbase[NBUCK];
    __shared__ int gbase[NBUCK];
    __shared__ int scanbuf[256];
    int base = blockIdx.x * CHUNK;
    int cnt = min(CHUNK, E - base);           // multiple of 4
    for (int i = t; i < NBUCK; i += 256) hist[i] = 0;
    __syncthreads();

    unsigned rec[16];
    unsigned br[16];                          // b (8b) | rank<<8
    bool valid[4];
    #pragma unroll
    for (int k = 0; k < 4; ++k) {
        int e0 = k * 1024 + t * 4;
        valid[k] = (e0 < cnt);
        if (valid[k]) {
            int4 s4 = *(const int4*)&src[base + e0];
            int4 d4 = *(const int4*)&dst[base + e0];
            int ss[4] = {s4.x, s4.y, s4.z, s4.w};
            int dd[4] = {d4.x, d4.y, d4.z, d4.w};
            #pragma unroll
            for (int j = 0; j < 4; ++j) {
                int b = dd[j] >> 9;
                int r = atomicAdd(&hist[b], 1);           // LDS atomic
                rec[k * 4 + j] = (unsigned)ss[j] | ((unsigned)(dd[j] & 511) << 17);
                br[k * 4 + j] = (unsigned)b | ((unsigned)r << 8);
            }
        }
    }
    __syncthreads();
    // inclusive Hillis-Steele scan over 256 (NBUCK padded)
    scanbuf[t] = (t < NBUCK) ? hist[t] : 0;
    __syncthreads();
    for (int s = 1; s < 256; s <<= 1) {
        int v = (t >= s) ? scanbuf[t - s] : 0;
        __syncthreads();
        scanbuf[t] += v;
        __syncthreads();
    }
    if (t < NBUCK) {
        lbase[t] = scanbuf[t] - hist[t];                  // exclusive base
        gbase[t] = atomicAdd(&gcursor[t], hist[t]);       // per-bucket global atomic
    }
    __syncthreads();
    // reorder into LDS, grouped by bucket
    #pragma unroll
    for (int k = 0; k < 4; ++k) {
        if (valid[k]) {
            #pragma unroll
            for (int j = 0; j < 4; ++j) {
                unsigned b = br[k * 4 + j] & 255u;
                unsigned r = br[k * 4 + j] >> 8;
                int p = lbase[b] + (int)r;
                srec[p] = rec[k * 4 + j];
                sb8[p] = (unsigned char)b;
            }
        }
    }
    __syncthreads();
    // dense flat write
    for (int i = t; i < cnt; i += 256) {
        int b = sb8[i];
        int pos = gbase[b] + (i - lbase[b]);
        if (pos < BBCAP) buckets[(size_t)b * BBCAP + pos] = srec[i];
    }
}

// ---------------- F2: count+isd+offsets+place (block-local)  ||  GEMM1 ----------------
// place blocks [0,NBUCK): LDS histogram of own bucket -> deg/isd/offsets -> CSR fill.
// gemm1 blocks [NBUCK, NBUCK+G1): h'[N+1,128](bf16) = x @ W1 (UNSCALED).
__global__ __launch_bounds__(256) void k_f2(const unsigned* __restrict__ buckets,
                                            const int* __restrict__ gcursor,
                                            int* __restrict__ deg,
                                            int* __restrict__ counter,
                                            int* __restrict__ offsets,
                                            float* __restrict__ isd,
                                            int* __restrict__ csr,
                                            const float* __restrict__ X,
                                            const unsigned short* __restrict__ w1s,
                                            unsigned short* __restrict__ H, int N) {
    __shared__ __align__(16) unsigned char SH[16384];
    int tid = threadIdx.x;
    if ((int)blockIdx.x < NBUCK) {
        int* s_deg = (int*)SH;                 // [512] degree histogram
        int* s_off = (int*)(SH + 2048);        // [512] absolute start offsets
        int* cur   = (int*)(SH + 4096);        // [512] live cursors
        int* sb    = (int*)(SH + 6144);        // [256] scan buffer
        int* sbase = (int*)(SH + 7168);        // [1]
        int b = blockIdx.x;
        int node0 = b << 9;
        int cnt = min(gcursor[b], BBCAP);
        const unsigned* bk = &buckets[(size_t)b * BBCAP];
        // pass 1: block-local degree histogram
        for (int i = tid; i < NPB; i += 256) s_deg[i] = 0;
        __syncthreads();
        for (int i = tid; i < cnt; i += 256)
            atomicAdd(&s_deg[bk[i] >> 17], 1);
        __syncthreads();
        // padded prefix scan over 512 node degrees (2 per thread)
        int i0 = tid * 2;
        int na = node0 + i0, nb = node0 + i0 + 1;
        int da = s_deg[i0], db = s_deg[i0 + 1];
        if (na >= N) da = 0;
        if (nb >= N) db = 0;
        int dpa = (da + 15) & ~15, dpb = (db + 15) & ~15;
        sb[tid] = dpa + dpb;
        __syncthreads();
        for (int s = 1; s < 256; s <<= 1) {
            int v = (tid >= s) ? sb[tid - s] : 0;
            __syncthreads();
            sb[tid] += v;
            __syncthreads();
        }
        int excl = sb[tid] - (dpa + dpb);
        if (tid == 0) *sbase = atomicAdd(counter, sb[255]);
        if (b == 0 && tid == 1) isd[N] = 0.f;          // dummy node
        __syncthreads();
        int offa = *sbase + excl;
        int offb = offa + dpa;
        if (na < N) {
            deg[na] = da; offsets[na] = offa;
            isd[na] = (da > 0) ? rsqrtf((float)da) : 0.f;
        }
        if (nb < N) {
            deg[nb] = db; offsets[nb] = offb;
            isd[nb] = (db > 0) ? rsqrtf((float)db) : 0.f;
        }
        s_off[i0] = offa; s_off[i0 + 1] = offb;
        s_deg[i0] = da;   s_deg[i0 + 1] = db;
        cur[i0] = offa;   cur[i0 + 1] = offb;
        __syncthreads();
        // pass 2: CSR fill
        for (int i = tid; i < cnt; i += 256) {
            unsigned r = bk[i];
            int p = atomicAdd(&cur[r >> 17], 1);
            csr[p] = (int)(r & 0x1FFFFu);
        }
        __syncthreads();
        // fill pad region with dummy node N (h'[N] = 0, h2'[N] = 0)
        for (int i = tid; i < NPB; i += 256) {
            int n = node0 + i;
            if (n < N) {
                int d = s_deg[i];
                int st = s_off[i] + d;
                int en = s_off[i] + ((d + 15) & ~15);
                for (int p = st; p < en; ++p) csr[p] = N;
            }
        }
        return;
    }
    // ---- GEMM1 (unscaled): h'[N+1,128](bf16) = x @ W1, MFMA 16x16x32 ----
    unsigned short* smem = (unsigned short*)SH;
    unsigned short* sA = smem;
    unsigned short* sB = smem + 2048;
    int lane = tid & 63;
    int wave = tid >> 6;
    int wr = wave >> 1;
    int wc = wave & 1;
    int m0 = (blockIdx.x - NBUCK) * 64;

    floatx4 acc[2][4] = {};

    for (int kt = 0; kt < 8; ++kt) {
        #pragma unroll
        for (int i = 0; i < 2; ++i) {
            int f = tid * 2 + i;
            int row = f >> 3;
            int c4 = (f & 7) * 4;
            float4 v = make_float4(0.f, 0.f, 0.f, 0.f);
            int grow = m0 + row;
            if (grow < N) v = *(const float4*)&X[(size_t)grow * 256 + kt * 32 + c4];
            int mt = row >> 4;
            int flane = (row & 15) | ((c4 >> 3) << 4);
            int j0 = c4 & 7;
            unsigned short* d = &sA[(size_t)(mt * 64 + flane) * 8 + j0];
            *(short4*)d = make_short4(f2bf(v.x), f2bf(v.y), f2bf(v.z), f2bf(v.w));
        }
        {
            const float4* srcp = (const float4*)&w1s[(size_t)kt * 4096];
            float4* dstp = (float4*)sB;
            dstp[tid] = srcp[tid];
            dstp[tid + 256] = srcp[tid + 256];
        }
        __syncthreads();
        bf16x8 a[2], b[4];
        #pragma unroll
        for (int p = 0; p < 2; ++p)
            a[p] = *(const bf16x8*)&sA[(size_t)((wr * 2 + p) * 64 + lane) * 8];
        #pragma unroll
        for (int q = 0; q < 4; ++q)
            b[q] = *(const bf16x8*)&sB[(size_t)((wc * 4 + q) * 64 + lane) * 8];
        #pragma unroll
        for (int p = 0; p < 2; ++p)
            #pragma unroll
            for (int q = 0; q < 4; ++q)
                acc[p][q] = __builtin_amdgcn_mfma_f32_16x16x32_bf16(a[p], b[q], acc[p][q], 0, 0, 0);
        __syncthreads();
    }
    #pragma unroll
    for (int p = 0; p < 2; ++p)
        #pragma unroll
        for (int q = 0; q < 4; ++q)
            #pragma unroll
            for (int r = 0; r < 4; ++r) {
                int rl = wr * 32 + p * 16 + ((lane >> 4) << 2) + r;
                int c = wc * 64 + q * 16 + (lane & 15);
                smem[rl * 128 + c] = f2bf(acc[p][q][r]);
            }
    __syncthreads();
    #pragma unroll
    for (int i = 0; i < 4; ++i) {
        int f = tid + i * 256;
        int row = f >> 4;
        int c8 = (f & 15) * 8;
        int grow = m0 + row;
        if (grow <= N)   // row N = zeros (A-tile zeros for grow>=N)
            *(float4*)&H[(size_t)grow * 128 + c8] = *(const float4*)&smem[row * 128 + c8];
    }
}

// ---------------- agg1: h1 = relu(b1 + isd_dst * sum isd_src * h'[src]) ----------------
// isd[s[j]] is wave-uniform -> scalar loads; v_add becomes v_fmac (SGPR operand).
__global__ __launch_bounds__(256) void k_agg1(const unsigned* __restrict__ Hu,
                                              const int* __restrict__ csr,
                                              const float* __restrict__ isd,
                                              const int* __restrict__ offsets,
                                              const int* __restrict__ deg,
                                              const float* __restrict__ b1,
                                              unsigned* __restrict__ H1u, int N) {
    int node = __builtin_amdgcn_readfirstlane((blockIdx.x * blockDim.x + threadIdx.x) >> 6);
    int lane = threadIdx.x & 63;
    if (node >= N) return;
    int start = offsets[node];
    int nb = (deg[node] + 15) >> 4;
    float isdn = isd[node];
    float acc0 = 0.f, acc1 = 0.f;
    for (int ib = 0; ib < nb; ++ib) {
        int b0 = start + ib * 16;
        int s[16];
        #pragma unroll
        for (int j = 0; j < 16; ++j) s[j] = csr[b0 + j];        // scalar loads
        float iss[16];
        #pragma unroll
        for (int j = 0; j < 16; ++j) iss[j] = isd[s[j]];        // scalar loads (isd[N]=0)
        unsigned p[16];
        #pragma unroll
        for (int j = 0; j < 16; ++j) p[j] = Hu[(size_t)s[j] * 64 + lane];
        #pragma unroll
        for (int j = 0; j < 16; ++j) {
            acc0 = fmaf(iss[j], bflo(p[j]), acc0);
            acc1 = fmaf(iss[j], bfhi(p[j]), acc1);
        }
    }
    float r0 = fmaxf(fmaf(isdn, acc0, b1[2 * lane]), 0.f);
    float r1 = fmaxf(fmaf(isdn, acc1, b1[2 * lane + 1]), 0.f);
    H1u[(size_t)node * 64 + lane] = (unsigned)f2bf(r0) | ((unsigned)f2bf(r1) << 16);
}

// ---------------- GEMM2: h2'[N+1,40](bf16) = isd*(h1 @ W2) ----------------
__global__ __launch_bounds__(256) void k_gemm2(const unsigned short* __restrict__ H1,
                                               const float* __restrict__ W2,
                                               const float* __restrict__ isd,
                                               unsigned short* __restrict__ H2, int N) {
    __shared__ float sH[64][132];
    __shared__ float sW[128 * 40];
    int tid = threadIdx.x;
    int block_row = blockIdx.x * 64;
    for (int i = tid; i < 64 * 16; i += 256) {
        int r = i >> 4;
        int c8 = (i & 15) * 8;
        int grow = block_row + r;
        uint4 v = make_uint4(0, 0, 0, 0);
        if (grow < N) v = *(const uint4*)&H1[(size_t)grow * 128 + c8];
        float* d = &sH[r][c8];
        d[0] = bflo(v.x); d[1] = bfhi(v.x);
        d[2] = bflo(v.y); d[3] = bfhi(v.y);
        d[4] = bflo(v.z); d[5] = bfhi(v.z);
        d[6] = bflo(v.w); d[7] = bfhi(v.w);
    }
    for (int i = tid; i < 1280; i += 256)
        *(float4*)&sW[i * 4] = *(const float4*)&W2[(size_t)i * 4];
    __syncthreads();

    int row = tid >> 2;
    int c0 = (tid & 3) * 10;
    float acc[10] = {};
    for (int k = 0; k < 128; ++k) {
        float hv = sH[row][k];
        #pragma unroll
        for (int j = 0; j < 5; ++j) {
            float2 wv = *(const float2*)&sW[k * 40 + c0 + 2 * j];
            acc[2 * j]     = fmaf(hv, wv.x, acc[2 * j]);
            acc[2 * j + 1] = fmaf(hv, wv.y, acc[2 * j + 1]);
        }
    }
    int grow = block_row + row;
    if (grow < N) {
        float scn = isd[grow];
        unsigned* o = (unsigned*)&H2[(size_t)grow * 40 + c0];
        #pragma unroll
        for (int j = 0; j < 5; ++j)
            o[j] = (unsigned)f2bf(acc[2 * j] * scn) |
                   ((unsigned)f2bf(acc[2 * j + 1] * scn) << 16);
    }
}

// ---------------- agg2: out = b2 + isdn * sum h2'[src] , C=40 ----------------
__global__ __launch_bounds__(256) void k_agg2(const unsigned* __restrict__ Hu2,
                                              const int* __restrict__ csr,
                                              const float* __restrict__ isd,
                                              const int* __restrict__ offsets,
                                              const int* __restrict__ deg,
                                              const float* __restrict__ b2,
                                              float* __restrict__ out, int N) {
    int node = __builtin_amdgcn_readfirstlane((blockIdx.x * blockDim.x + threadIdx.x) >> 6);
    int lane = threadIdx.x & 63;
    if (node >= N) return;
    int start = offsets[node];
    int nb = (deg[node] + 15) >> 4;
    float isdn = isd[node];
    int sub = lane >> 5;       // 0/1
    int c = lane & 31;         // active c<20; c in [20,32) reads slack (finite, unused)
    float acc0 = 0.f, acc1 = 0.f;
    for (int ib = 0; ib < nb; ++ib) {
        int b0 = start + ib * 16;
        #pragma unroll
        for (int j = 0; j < 8; ++j) {
            int s = csr[b0 + (j << 1) + sub];
            unsigned q = Hu2[(size_t)s * 20 + c];
            acc0 += bflo(q);
            acc1 += bfhi(q);
        }
    }
    acc0 += __shfl(acc0, lane + 32);
    acc1 += __shfl(acc1, lane + 32);
    if (lane < 20)
        *(float2*)&out[(size_t)node * 40 + 2 * lane] =
            make_float2(fmaf(isdn, acc0, b2[2 * lane]), fmaf(isdn, acc1, b2[2 * lane + 1]));
}

extern "C" void kernel_launch(void* const* d_in, const int* in_sizes, int n_in,
                              void* d_out, int out_size, void* d_ws, size_t ws_size,
                              hipStream_t stream) {
    const float* x  = (const float*)d_in[0];
    const int*  src = (const int*)d_in[1];
    const int*  dst = (const int*)d_in[2];
    const float* W1 = (const float*)d_in[3];
    const float* b1 = (const float*)d_in[4];
    const float* W2 = (const float*)d_in[5];
    const float* b2 = (const float*)d_in[6];
    float* out = (float*)d_out;

    const int N = in_sizes[0] / 256;   // 100000
    const int E = in_sizes[1];         // 1600000

    char* w = (char*)d_ws;
    auto alloc = [&](size_t bytes) -> void* {
        void* p = (void*)w;
        w += (bytes + 15) & ~(size_t)15;
        return p;
    };
    int*      gcursor = (int*)alloc(256 * 4);                 // zeroed
    int*      counter = (int*)alloc(16);                      // zeroed
    int*      deg     = (int*)alloc((size_t)N * 4);           // written by f2
    float*    isd     = (float*)alloc((size_t)(N + 1) * 4);
    int*      offsets = (int*)alloc((size_t)(N + 1) * 4);
    unsigned* buckets = (unsigned*)alloc((size_t)NBUCK * BBCAP * 4);
    int*      csr     = (int*)alloc((size_t)(E + 16 * (size_t)N) * 4);
    unsigned short* w1s = (unsigned short*)alloc(32768 * 2);
    unsigned short* h   = (unsigned short*)alloc((size_t)(N + 1) * 128 * 2);  // h'
    unsigned short* h1  = (unsigned short*)alloc((size_t)N * 128 * 2);
    unsigned short* h2  = (unsigned short*)alloc(((size_t)(N + 1) * 20 + 16) * 4);  // h2'

    hipMemsetAsync(gcursor, 0, 256 * 4 + 16, stream);

    int nchunk = (E + CHUNK - 1) / CHUNK;   // 392
    int G1 = (N + 63) / 64;                 // 1563
    k_f1<<<nchunk + 16, 256, 0, stream>>>(src, dst, gcursor, buckets, E, nchunk,
                                          W1, w1s, (unsigned*)h2 + (size_t)N * 20);
    k_f2<<<NBUCK + G1, 256, 0, stream>>>(buckets, gcursor, deg, counter, offsets, isd,
                                         csr, x, w1s, h, N);
    k_agg1<<<(N + 3) / 4, 256, 0, stream>>>((const unsigned*)h, csr, isd, offsets, deg,
                                            b1, (unsigned*)h1, N);
    k_gemm2<<<G1, 256, 0, stream>>>(h1, W2, isd, h2, N);
    k_agg2<<<(N + 3) / 4, 256, 0, stream>>>((const unsigned*)h2, csr, isd, offsets, deg,
                                            b2, out, N);
}